// Round 17
// baseline (186.312 us; speedup 1.0000x reference)
//
#include <hip/hip_runtime.h>
#include <hip/hip_fp16.h>
#include <cstdint>

typedef int v4i __attribute__((ext_vector_type(4)));

#define AS1C(p) ((const __attribute__((address_space(1))) void*)(p))
#define AS3(p)  ((__attribute__((address_space(3))) void*)(p))

// ---------------------------------------------------------------------------
// Fused per-row symmetric int8 quantization (single pass, row in registers).
// ---------------------------------------------------------------------------
__global__ __launch_bounds__(256) void quant_fused(const float* __restrict__ X,
                                                   const float* __restrict__ W,
                                                   int8_t* __restrict__ Xq,
                                                   int8_t* __restrict__ Wq,
                                                   float* __restrict__ a_scale,
                                                   float* __restrict__ w_scale) {
    const int row = blockIdx.x;
    const float* src;
    int8_t* dst;
    float* scp;
    if (row < 8192) {
        src = X + (size_t)row * 4096;  dst = Xq + (size_t)row * 4096;  scp = a_scale + row;
    } else {
        const int r = row - 8192;
        src = W + (size_t)r * 4096;    dst = Wq + (size_t)r * 4096;    scp = w_scale + r;
    }
    const float4* xv = (const float4*)src;

    float4 v[4];
#pragma unroll
    for (int j = 0; j < 4; ++j) v[j] = xv[threadIdx.x + (j << 8)];

    float m = 0.0f;
#pragma unroll
    for (int j = 0; j < 4; ++j) {
        m = fmaxf(m, fmaxf(fmaxf(fabsf(v[j].x), fabsf(v[j].y)),
                           fmaxf(fabsf(v[j].z), fabsf(v[j].w))));
    }
    for (int off = 32; off > 0; off >>= 1)
        m = fmaxf(m, __shfl_xor(m, off, 64));

    __shared__ float wmax[4];
    __shared__ float s_sc;
    const int lane = threadIdx.x & 63;
    const int wv = threadIdx.x >> 6;
    if (lane == 0) wmax[wv] = m;
    __syncthreads();
    if (threadIdx.x == 0) {
        float mm = fmaxf(fmaxf(wmax[0], wmax[1]), fmaxf(wmax[2], wmax[3]));
        float sc = mm / 127.0f;
        *scp = sc;
        s_sc = sc;
    }
    __syncthreads();
    const float sc = s_sc;

    char4* qv = (char4*)dst;
#pragma unroll
    for (int j = 0; j < 4; ++j) {
        char4 q;
        q.x = (signed char)(int)rintf(v[j].x / sc);
        q.y = (signed char)(int)rintf(v[j].y / sc);
        q.z = (signed char)(int)rintf(v[j].z / sc);
        q.w = (signed char)(int)rintf(v[j].w / sc);
        qv[threadIdx.x + (j << 8)] = q;
    }
}

// ---------------------------------------------------------------------------
// int8 GEMM, 256x256 tile, 512 threads = 8 waves (2M x 4N), per-wave 128x64.
// FAITHFUL m201 8-PHASE PORT (the verified 62%-MfmaUtil bf16 structure):
// per K-tile = 4 phases; phase q = { ds_read A-pair 2q,2q+1 (+ all 4 B in
// phase 0) from the CURRENT buffer ; issue 1 staging load for tile kt+3 ;
// s_barrier ; lgkmcnt(0)+sched_barrier ; setprio(1) 8 MFMA setprio(0) ;
// [phase 3: vmcnt(8)] ; s_barrier }.
// WHY (r3/r6/r7 post-mortem): those schedules decoupled reads from their
// consuming MFMAs (cross-tile reg prefetch, tile-level gating) — waves
// re-synced into the same pipe-phase each tile and LDS-port time ADDED to
// MFMA time (~52% wall). m201's phase-local {barrier; lgkmcnt(0); MFMA}
// staggers waves WITHIN each phase: first-drained waves start their MFMA
// cluster while the port drains the rest — the overlap mechanism this
// session never actually ran. Counted vmcnt(8) once per tile (T4: retires
// exactly tile kt+1's 4 loads; 8 stay in flight across barriers).
// Ring audit: phase reads of buf kt&3 follow the end-of-(kt-1) barrier
// which follows the vmcnt that retired kt's staging; stage(kt+3) issues
// after every wave's reads of that buffer were lgkm-drained a tile ago;
// tail clamps to 63 = idempotent duplicate writes of identical bytes.
// ---------------------------------------------------------------------------
__global__ __launch_bounds__(512, 2) void gemm_i8(const int8_t* __restrict__ Aq,
                                                  const int8_t* __restrict__ Bq,
                                                  const float* __restrict__ a_scale,
                                                  const float* __restrict__ w_scale,
                                                  float* __restrict__ out) {
    extern __shared__ __align__(16) int8_t smem[];  // 4 x (A 16K | B 16K)

    const int K = 4096;
    const int bid = blockIdx.x;
    const int wg  = (bid & 7) * 64 + (bid >> 3);  // bijective: 512 = 8 x 64
    const int n0 = (wg & 15) * 256;
    const int m0 = (wg >> 4) * 256;

    const int tid  = threadIdx.x;
    const int lane = tid & 63;
    const int wid  = tid >> 6;
    const int wm   = wid >> 2;
    const int wn   = wid & 3;

    // fragment read offsets (64-B rows, 16-B-chunk XOR swizzle)
    const int rsel  = lane & 15;
    const int kswz  = ((lane >> 4) << 4) ^ (((rsel >> 1) & 3) << 4);
    const int abase = (wm * 128 + rsel) * 64 + kswz;
    const int bbase = 16384 + (wn * 64 + rsel) * 64 + kswz;

    // staging: 512 thr x 16 B = 8 KB/issue = 128 rows; pre-swizzled source
    const int strow = tid >> 2;
    const int stswz = ((strow >> 1) & 3) << 4;
    const int stcol = ((tid & 3) << 4) ^ stswz;
    const int8_t* gA = Aq + (size_t)(m0 + strow) * K + stcol;
    const int8_t* gB = Bq + (size_t)(n0 + strow) * K + stcol;
    const size_t rstep = (size_t)128 * K;
    const int ldsst = wid * 1024;  // + lane*16 by HW

    v4i acc[8][4] = {};
    v4i aF[8], bF[4];

#define STAGE(buf, kt) do {                                                          \
    int8_t* _d = smem + (buf) * 32768;                                               \
    const int8_t* _sa = gA + (size_t)(kt) * 64;                                      \
    const int8_t* _sb = gB + (size_t)(kt) * 64;                                      \
    __builtin_amdgcn_global_load_lds(AS1C(_sa),         AS3(_d + ldsst),         16, 0, 0); \
    __builtin_amdgcn_global_load_lds(AS1C(_sa + rstep), AS3(_d + 8192  + ldsst), 16, 0, 0); \
    __builtin_amdgcn_global_load_lds(AS1C(_sb),         AS3(_d + 16384 + ldsst), 16, 0, 0); \
    __builtin_amdgcn_global_load_lds(AS1C(_sb + rstep), AS3(_d + 24576 + ldsst), 16, 0, 0); \
  } while (0)

    // One phase: reads for THIS phase's MFMAs; 1 staging issue; barrier;
    // full lgkm drain (m201 discipline); MFMA burst; [last: vmcnt]; barrier.
#define PHASE(q, gsrc, goff, last) do {                                              \
    if ((q) == 0) {                                                                  \
        bF[0] = *(const v4i*)(bufc + bbase);                                         \
        bF[1] = *(const v4i*)(bufc + bbase + 1024);                                  \
        bF[2] = *(const v4i*)(bufc + bbase + 2048);                                  \
        bF[3] = *(const v4i*)(bufc + bbase + 3072);                                  \
    }                                                                                \
    aF[2*(q)]     = *(const v4i*)(bufc + abase + (2*(q))     * 1024);                \
    aF[2*(q) + 1] = *(const v4i*)(bufc + abase + (2*(q) + 1) * 1024);                \
    __builtin_amdgcn_global_load_lds(AS1C(gsrc), AS3(pD + (goff) + ldsst), 16, 0, 0);\
    __builtin_amdgcn_s_barrier();                                                    \
    asm volatile("s_waitcnt lgkmcnt(0)" ::: "memory");                               \
    __builtin_amdgcn_sched_barrier(0);                                               \
    __builtin_amdgcn_s_setprio(1);                                                   \
    _Pragma("unroll")                                                                \
    for (int nt = 0; nt < 4; ++nt) {                                                 \
        acc[2*(q)][nt] = __builtin_amdgcn_mfma_i32_16x16x64_i8(                      \
            aF[2*(q)], bF[nt], acc[2*(q)][nt], 0, 0, 0);                             \
        acc[2*(q)+1][nt] = __builtin_amdgcn_mfma_i32_16x16x64_i8(                    \
            aF[2*(q)+1], bF[nt], acc[2*(q)+1][nt], 0, 0, 0);                         \
    }                                                                                \
    __builtin_amdgcn_s_setprio(0);                                                   \
    if (last) asm volatile("s_waitcnt vmcnt(8)" ::: "memory");                       \
    __builtin_amdgcn_s_barrier();                                                    \
  } while (0)

#define KSTEP(u, kt4) do {                                                           \
    const int kt  = (kt4) + (u);                                                     \
    const int8_t* bufc = smem + (u) * 32768;                                         \
    int8_t* pD = smem + (((u) + 3) & 3) * 32768;                                     \
    const int ktp = (kt + 3 < 64) ? (kt + 3) : 63;                                   \
    const int8_t* _a = gA + (size_t)ktp * 64;                                        \
    const int8_t* _b = gB + (size_t)ktp * 64;                                        \
    PHASE(0, _a,         0,     0);                                                  \
    PHASE(1, _a + rstep, 8192,  0);                                                  \
    PHASE(2, _b,         16384, 0);                                                  \
    PHASE(3, _b + rstep, 24576, 1);                                                  \
  } while (0)

    // ---- prologue: stage tiles 0..2; retire tile 0; enter phase loop
    STAGE(0, 0); STAGE(1, 1); STAGE(2, 2);
    asm volatile("s_waitcnt vmcnt(8)" ::: "memory");
    __builtin_amdgcn_s_barrier();

    for (int kt4 = 0; kt4 < 64; kt4 += 4) {
        KSTEP(0, kt4);
        KSTEP(1, kt4);
        KSTEP(2, kt4);
        KSTEP(3, kt4);
    }

    // epilogue: C/D layout col = lane&15 (N), row = (lane>>4)*4 + reg (M)
    const int r0  = (lane >> 4) << 2;
    const int col = lane & 15;
#pragma unroll
    for (int mt = 0; mt < 8; ++mt) {
        const int tbase = m0 + wm * 128 + mt * 16 + r0;
        float as[4];
#pragma unroll
        for (int r = 0; r < 4; ++r) as[r] = a_scale[tbase + r];
#pragma unroll
        for (int nt = 0; nt < 4; ++nt) {
            const int o = n0 + wn * 64 + nt * 16 + col;
            const float wsc = w_scale[o];
#pragma unroll
            for (int r = 0; r < 4; ++r) {
                float v = (float)acc[mt][nt][r] * as[r] * wsc;
                out[(size_t)(tbase + r) * 4096 + o] = __half2float(__float2half_rn(v));
            }
        }
    }
#undef KSTEP
#undef PHASE
#undef STAGE
}

extern "C" void kernel_launch(void* const* d_in, const int* in_sizes, int n_in,
                              void* d_out, int out_size, void* d_ws, size_t ws_size,
                              hipStream_t stream) {
    const float* input_act = (const float*)d_in[0];  // [4,2048,4096] = [8192,4096]
    const float* weight    = (const float*)d_in[1];  // [4096,4096]
    float* out = (float*)d_out;

    const int K = 4096, O = 4096, T = 8192;

    int8_t* x_q = (int8_t*)d_ws;
    int8_t* w_q = x_q + (size_t)T * K;
    float* a_scale = (float*)(w_q + (size_t)O * K);
    float* w_scale = a_scale + T;

    static bool attr_done = false;
    if (!attr_done) {
        hipFuncSetAttribute(reinterpret_cast<const void*>(gemm_i8),
                            hipFuncAttributeMaxDynamicSharedMemorySize, 131072);
        attr_done = true;
    }

    quant_fused<<<T + O, 256, 0, stream>>>(input_act, weight, x_q, w_q,
                                           a_scale, w_scale);

    dim3 grid(512);  // (8192/256) x (4096/256), XCD-swizzled in-kernel
    gemm_i8<<<grid, 512, 131072, stream>>>(x_q, w_q, a_scale, w_scale, out);
}

// Round 18
// 182.345 us; speedup vs baseline: 1.0218x; 1.0218x over previous
//
#include <hip/hip_runtime.h>
#include <hip/hip_fp16.h>
#include <cstdint>

typedef int v4i __attribute__((ext_vector_type(4)));

#define AS1C(p) ((const __attribute__((address_space(1))) void*)(p))
#define AS3(p)  ((__attribute__((address_space(3))) void*)(p))

// ---------------------------------------------------------------------------
// Fused per-row symmetric int8 quantization (single pass, row in registers).
// ---------------------------------------------------------------------------
__global__ __launch_bounds__(256) void quant_fused(const float* __restrict__ X,
                                                   const float* __restrict__ W,
                                                   int8_t* __restrict__ Xq,
                                                   int8_t* __restrict__ Wq,
                                                   float* __restrict__ a_scale,
                                                   float* __restrict__ w_scale) {
    const int row = blockIdx.x;
    const float* src;
    int8_t* dst;
    float* scp;
    if (row < 8192) {
        src = X + (size_t)row * 4096;  dst = Xq + (size_t)row * 4096;  scp = a_scale + row;
    } else {
        const int r = row - 8192;
        src = W + (size_t)r * 4096;    dst = Wq + (size_t)r * 4096;    scp = w_scale + r;
    }
    const float4* xv = (const float4*)src;

    float4 v[4];
#pragma unroll
    for (int j = 0; j < 4; ++j) v[j] = xv[threadIdx.x + (j << 8)];

    float m = 0.0f;
#pragma unroll
    for (int j = 0; j < 4; ++j) {
        m = fmaxf(m, fmaxf(fmaxf(fabsf(v[j].x), fabsf(v[j].y)),
                           fmaxf(fabsf(v[j].z), fabsf(v[j].w))));
    }
    for (int off = 32; off > 0; off >>= 1)
        m = fmaxf(m, __shfl_xor(m, off, 64));

    __shared__ float wmax[4];
    __shared__ float s_sc;
    const int lane = threadIdx.x & 63;
    const int wv = threadIdx.x >> 6;
    if (lane == 0) wmax[wv] = m;
    __syncthreads();
    if (threadIdx.x == 0) {
        float mm = fmaxf(fmaxf(wmax[0], wmax[1]), fmaxf(wmax[2], wmax[3]));
        float sc = mm / 127.0f;
        *scp = sc;
        s_sc = sc;
    }
    __syncthreads();
    const float sc = s_sc;

    char4* qv = (char4*)dst;
#pragma unroll
    for (int j = 0; j < 4; ++j) {
        char4 q;
        q.x = (signed char)(int)rintf(v[j].x / sc);
        q.y = (signed char)(int)rintf(v[j].y / sc);
        q.z = (signed char)(int)rintf(v[j].z / sc);
        q.w = (signed char)(int)rintf(v[j].w / sc);
        qv[threadIdx.x + (j << 8)] = q;
    }
}

// ---------------------------------------------------------------------------
// int8 GEMM, 256x256 tile, 512 threads = 8 waves (2M x 4N), per-wave 128x64.
// 4-buffer LDS ring (128 KiB), BK=64 B, register-double-buffered fragments,
// counted vmcnt(4) + ONE barrier per K-tile.
// THIS ROUND (single variable vs r7): ALL intra-tile scheduling directives
// removed — no sched_barrier fences, no setprio, no role split. The reads
// target NEXT-tile registers (zero dependence on current MFMAs), so the
// compiler is free to emit its m97-style fine interleave: counted
// lgkmcnt(N) per consumer, MFMAs starting as soon as operands land, reads
// and staging issues hidden under the MFMA stream WITHIN each wave.
// Schedule-matrix record: manual bulk fencing = 52% MfmaUtil wall
// (r3/r6/r7); per-phase drain+double-barrier = 41.7% (r17); this is the
// unexplored cell: counted-vmcnt ring + full compiler freedom (m141
// lesson: order-pinning defeats the scheduler; m97: unfenced bodies get
// fine-grained lgkmcnt interleave).
// Ring audit (identical to r2, which passed): reads of buf[(kt+1)&3]
// follow every wave's vmcnt(4) + barrier (writes retired block-wide);
// STAGE into buf[(kt+3)&3] overwrites tile kt-1, whose last reads were
// lgkm-complete before kt-1's MFMAs, which precede this tile's barrier.
// ---------------------------------------------------------------------------
__global__ __launch_bounds__(512, 2) void gemm_i8(const int8_t* __restrict__ Aq,
                                                  const int8_t* __restrict__ Bq,
                                                  const float* __restrict__ a_scale,
                                                  const float* __restrict__ w_scale,
                                                  float* __restrict__ out) {
    extern __shared__ __align__(16) int8_t smem[];  // 4 x (A 16K | B 16K)

    const int K = 4096;
    const int bid = blockIdx.x;
    const int wg  = (bid & 7) * 64 + (bid >> 3);  // bijective: 512 = 8 x 64
    const int n0 = (wg & 15) * 256;
    const int m0 = (wg >> 4) * 256;

    const int tid  = threadIdx.x;
    const int lane = tid & 63;
    const int wid  = tid >> 6;
    const int wm   = wid >> 2;
    const int wn   = wid & 3;

    // fragment read offsets (64-B rows, 16-B-chunk XOR swizzle)
    const int rsel  = lane & 15;
    const int kswz  = ((lane >> 4) << 4) ^ (((rsel >> 1) & 3) << 4);
    const int abase = (wm * 128 + rsel) * 64 + kswz;
    const int bbase = 16384 + (wn * 64 + rsel) * 64 + kswz;

    // staging: 512 thr x 16 B = 128 rows/issue; pre-swizzled global source
    const int strow = tid >> 2;
    const int stswz = ((strow >> 1) & 3) << 4;
    const int stcol = ((tid & 3) << 4) ^ stswz;
    const int8_t* gA = Aq + (size_t)(m0 + strow) * K + stcol;
    const int8_t* gB = Bq + (size_t)(n0 + strow) * K + stcol;
    const size_t rstep = (size_t)128 * K;
    const int ldsst = wid * 1024;  // + lane*16 by HW

    v4i acc[8][4] = {};
    v4i aFa[8], aFb[8], bFa[4], bFb[4];

#define STAGE(buf, kt) do {                                                          \
    int8_t* _d = smem + (buf) * 32768;                                               \
    const int8_t* _a = gA + (size_t)(kt) * 64;                                       \
    const int8_t* _b = gB + (size_t)(kt) * 64;                                       \
    __builtin_amdgcn_global_load_lds(AS1C(_a),         AS3(_d + ldsst),         16, 0, 0); \
    __builtin_amdgcn_global_load_lds(AS1C(_a + rstep), AS3(_d + 8192  + ldsst), 16, 0, 0); \
    __builtin_amdgcn_global_load_lds(AS1C(_b),         AS3(_d + 16384 + ldsst), 16, 0, 0); \
    __builtin_amdgcn_global_load_lds(AS1C(_b + rstep), AS3(_d + 24576 + ldsst), 16, 0, 0); \
  } while (0)

    // One K-tile: consume CA/CB (tile kt, in regs), prefetch NA/NB (kt+1).
    // NO fences, NO setprio — compiler owns the intra-tile schedule.
#define KSTEP(u, CA, CB, NA, NB, kt4) do {                                           \
    const int kt  = (kt4) + (u);                                                     \
    const int8_t* bufN = smem + (((u) + 1) & 3) * 32768;                             \
    const int ktp = (kt + 3 < 64) ? (kt + 3) : 63;                                   \
    asm volatile("s_waitcnt vmcnt(4)" ::: "memory");                                 \
    __builtin_amdgcn_s_barrier();                                                    \
    _Pragma("unroll")                                                                \
    for (int mt = 0; mt < 8; ++mt)                                                   \
        NA[mt] = *(const v4i*)(bufN + abase + mt * 1024);                            \
    _Pragma("unroll")                                                                \
    for (int nt = 0; nt < 4; ++nt)                                                   \
        NB[nt] = *(const v4i*)(bufN + bbase + nt * 1024);                            \
    STAGE(((u) + 3) & 3, ktp);                                                       \
    _Pragma("unroll")                                                                \
    for (int mt = 0; mt < 8; ++mt)                                                   \
        _Pragma("unroll")                                                            \
        for (int nt = 0; nt < 4; ++nt)                                               \
            acc[mt][nt] = __builtin_amdgcn_mfma_i32_16x16x64_i8(                     \
                CA[mt], CB[nt], acc[mt][nt], 0, 0, 0);                               \
  } while (0)

    // ---- prologue: stage tiles 0..2; retire tile 0; load its fragments
    STAGE(0, 0); STAGE(1, 1); STAGE(2, 2);
    asm volatile("s_waitcnt vmcnt(8)" ::: "memory");
    __builtin_amdgcn_s_barrier();
#pragma unroll
    for (int mt = 0; mt < 8; ++mt) aFa[mt] = *(const v4i*)(smem + abase + mt * 1024);
#pragma unroll
    for (int nt = 0; nt < 4; ++nt) bFa[nt] = *(const v4i*)(smem + bbase + nt * 1024);

    for (int kt4 = 0; kt4 < 64; kt4 += 4) {
        KSTEP(0, aFa, bFa, aFb, bFb, kt4);
        KSTEP(1, aFb, bFb, aFa, bFa, kt4);
        KSTEP(2, aFa, bFa, aFb, bFb, kt4);
        KSTEP(3, aFb, bFb, aFa, bFa, kt4);
    }

    // epilogue: C/D layout col = lane&15 (N), row = (lane>>4)*4 + reg (M)
    const int r0  = (lane >> 4) << 2;
    const int col = lane & 15;
#pragma unroll
    for (int mt = 0; mt < 8; ++mt) {
        const int tbase = m0 + wm * 128 + mt * 16 + r0;
        float as[4];
#pragma unroll
        for (int r = 0; r < 4; ++r) as[r] = a_scale[tbase + r];
#pragma unroll
        for (int nt = 0; nt < 4; ++nt) {
            const int o = n0 + wn * 64 + nt * 16 + col;
            const float wsc = w_scale[o];
#pragma unroll
            for (int r = 0; r < 4; ++r) {
                float v = (float)acc[mt][nt][r] * as[r] * wsc;
                out[(size_t)(tbase + r) * 4096 + o] = __half2float(__float2half_rn(v));
            }
        }
    }
#undef KSTEP
#undef STAGE
}

extern "C" void kernel_launch(void* const* d_in, const int* in_sizes, int n_in,
                              void* d_out, int out_size, void* d_ws, size_t ws_size,
                              hipStream_t stream) {
    const float* input_act = (const float*)d_in[0];  // [4,2048,4096] = [8192,4096]
    const float* weight    = (const float*)d_in[1];  // [4096,4096]
    float* out = (float*)d_out;

    const int K = 4096, O = 4096, T = 8192;

    int8_t* x_q = (int8_t*)d_ws;
    int8_t* w_q = x_q + (size_t)T * K;
    float* a_scale = (float*)(w_q + (size_t)O * K);
    float* w_scale = a_scale + T;

    static bool attr_done = false;
    if (!attr_done) {
        hipFuncSetAttribute(reinterpret_cast<const void*>(gemm_i8),
                            hipFuncAttributeMaxDynamicSharedMemorySize, 131072);
        attr_done = true;
    }

    quant_fused<<<T + O, 256, 0, stream>>>(input_act, weight, x_q, w_q,
                                           a_scale, w_scale);

    dim3 grid(512);  // (8192/256) x (4096/256), XCD-swizzled in-kernel
    gemm_i8<<<grid, 512, 131072, stream>>>(x_q, w_q, a_scale, w_scale, out);
}

// Round 19
// 176.774 us; speedup vs baseline: 1.0540x; 1.0315x over previous
//
#include <hip/hip_runtime.h>
#include <hip/hip_fp16.h>
#include <cstdint>

typedef int v4i __attribute__((ext_vector_type(4)));

#define AS1C(p) ((const __attribute__((address_space(1))) void*)(p))
#define AS3(p)  ((__attribute__((address_space(3))) void*)(p))

// ---------------------------------------------------------------------------
// Fused per-row symmetric int8 quantization. Single pass, row in registers.
// THIS ROUND: each thread owns 64 contiguous bytes of the row -> quantized
// output packs into ONE 16-B store per thread (was 4x char4 scatter, G13).
// Same arithmetic per element (rintf(x/sc)) — only thread<->element
// assignment changed.
// ---------------------------------------------------------------------------
__global__ __launch_bounds__(256) void quant_fused(const float* __restrict__ X,
                                                   const float* __restrict__ W,
                                                   int8_t* __restrict__ Xq,
                                                   int8_t* __restrict__ Wq,
                                                   float* __restrict__ a_scale,
                                                   float* __restrict__ w_scale) {
    const int row = blockIdx.x;
    const float* src;
    int8_t* dst;
    float* scp;
    if (row < 8192) {
        src = X + (size_t)row * 4096;  dst = Xq + (size_t)row * 4096;  scp = a_scale + row;
    } else {
        const int r = row - 8192;
        src = W + (size_t)r * 4096;    dst = Wq + (size_t)r * 4096;    scp = w_scale + r;
    }
    const float4* xv = (const float4*)src;
    const int tid = threadIdx.x;

    float4 v[4];
#pragma unroll
    for (int j = 0; j < 4; ++j) v[j] = xv[tid * 4 + j];  // 64 contiguous bytes/thread

    float m = 0.0f;
#pragma unroll
    for (int j = 0; j < 4; ++j) {
        m = fmaxf(m, fmaxf(fmaxf(fabsf(v[j].x), fabsf(v[j].y)),
                           fmaxf(fabsf(v[j].z), fabsf(v[j].w))));
    }
    for (int off = 32; off > 0; off >>= 1)
        m = fmaxf(m, __shfl_xor(m, off, 64));

    __shared__ float wmax[4];
    __shared__ float s_sc;
    const int lane = tid & 63;
    const int wv = tid >> 6;
    if (lane == 0) wmax[wv] = m;
    __syncthreads();
    if (tid == 0) {
        float mm = fmaxf(fmaxf(wmax[0], wmax[1]), fmaxf(wmax[2], wmax[3]));
        float sc = mm / 127.0f;
        *scp = sc;
        s_sc = sc;
    }
    __syncthreads();
    const float sc = s_sc;

    v4i qw;
#pragma unroll
    for (int j = 0; j < 4; ++j) {
        const int b0 = (int)(unsigned char)(signed char)(int)rintf(v[j].x / sc);
        const int b1 = (int)(unsigned char)(signed char)(int)rintf(v[j].y / sc);
        const int b2 = (int)(unsigned char)(signed char)(int)rintf(v[j].z / sc);
        const int b3 = (int)(signed char)(int)rintf(v[j].w / sc);
        qw[j] = b0 | (b1 << 8) | (b2 << 16) | (b3 << 24);
    }
    *(v4i*)(dst + (size_t)tid * 16) = qw;  // one 16-B store (1 KB/wave/instr)
}

// ---------------------------------------------------------------------------
// int8 GEMM — r7 VERBATIM (best verified: gemm 125-127 µs, MfmaUtil ~52%,
// bank conflicts 0, VGPR 120). 256x256 tile, 512 threads = 8 waves (2M x
// 4N), per-wave 128x64; 4-buffer LDS ring (128 KiB); register-double-
// buffered fragments; 4 groups/tile {3 ds_read + 1 global_load_lds +
// 8 MFMA}; static role split by SIMD sibling; setprio on MFMA clusters.
// Session schedule matrix (r3-r18): bulk-fenced 52% / fine-fenced 50% /
// T5-scoped 52% / role-split 52% / unfenced 43% / 8-phase-drain 42% /
// 2-blk-CU 42% — the LDS-port (~1400 cyc/tile) vs MFMA (~1306 cyc/tile)
// serialization is structural at this wave-tile shape; larger tiles spill
// (r10/r12) or miscompile via AGPR asm (r13/r14); B-bypass loses on vmem
// (r8/r9). r7 is the measured optimum of the family.
// ---------------------------------------------------------------------------
__global__ __launch_bounds__(512, 2) void gemm_i8(const int8_t* __restrict__ Aq,
                                                  const int8_t* __restrict__ Bq,
                                                  const float* __restrict__ a_scale,
                                                  const float* __restrict__ w_scale,
                                                  float* __restrict__ out) {
    extern __shared__ __align__(16) int8_t smem[];  // 4 x (A 16K | B 16K)

    const int K = 4096;
    const int bid = blockIdx.x;
    const int wg  = (bid & 7) * 64 + (bid >> 3);  // bijective: 512 = 8 x 64
    const int n0 = (wg & 15) * 256;
    const int m0 = (wg >> 4) * 256;

    const int tid  = threadIdx.x;
    const int lane = tid & 63;
    const int wid  = tid >> 6;
    const int wm   = wid >> 2;
    const int wn   = wid & 3;

    // fragment read offsets (64-B rows, 16-B-chunk XOR swizzle)
    const int rsel  = lane & 15;
    const int kswz  = ((lane >> 4) << 4) ^ (((rsel >> 1) & 3) << 4);
    const int abase = (wm * 128 + rsel) * 64 + kswz;
    const int bbase = 16384 + (wn * 64 + rsel) * 64 + kswz;

    // staging: 512 thr x 16 B = 128 rows/issue; pre-swizzled global source
    const int strow = tid >> 2;
    const int stswz = ((strow >> 1) & 3) << 4;
    const int stcol = ((tid & 3) << 4) ^ stswz;
    const int8_t* gA = Aq + (size_t)(m0 + strow) * K + stcol;
    const int8_t* gB = Bq + (size_t)(n0 + strow) * K + stcol;
    const size_t rstep = (size_t)128 * K;
    const int ldsst = wid * 1024;  // + lane*16 by HW

    v4i acc[8][4] = {};
    v4i aFa[8], aFb[8], bFa[4], bFb[4];

#define STAGE(buf, kt) do {                                                          \
    int8_t* _d = smem + (buf) * 32768;                                               \
    const int8_t* _a = gA + (size_t)(kt) * 64;                                       \
    const int8_t* _b = gB + (size_t)(kt) * 64;                                       \
    __builtin_amdgcn_global_load_lds(AS1C(_a),         AS3(_d + ldsst),         16, 0, 0); \
    __builtin_amdgcn_global_load_lds(AS1C(_a + rstep), AS3(_d + 8192  + ldsst), 16, 0, 0); \
    __builtin_amdgcn_global_load_lds(AS1C(_b),         AS3(_d + 16384 + ldsst), 16, 0, 0); \
    __builtin_amdgcn_global_load_lds(AS1C(_b + rstep), AS3(_d + 24576 + ldsst), 16, 0, 0); \
  } while (0)

#define READS(g, NA, NB, gsrc, goff) do {                                            \
    NA[2*(g)]     = *(const v4i*)(bufN + abase + (2*(g))     * 1024);                \
    NA[2*(g) + 1] = *(const v4i*)(bufN + abase + (2*(g) + 1) * 1024);                \
    NB[(g)]       = *(const v4i*)(bufN + bbase + (g) * 1024);                        \
    __builtin_amdgcn_global_load_lds(AS1C(gsrc), AS3(pD + (goff) + ldsst), 16, 0, 0);\
  } while (0)

#define MFMAS(g, CA, CB) do {                                                        \
    __builtin_amdgcn_s_setprio(1);                                                   \
    _Pragma("unroll")                                                                \
    for (int nt = 0; nt < 4; ++nt) {                                                 \
        acc[2*(g)][nt] = __builtin_amdgcn_mfma_i32_16x16x64_i8(                      \
            CA[2*(g)], CB[nt], acc[2*(g)][nt], 0, 0, 0);                             \
        acc[2*(g)+1][nt] = __builtin_amdgcn_mfma_i32_16x16x64_i8(                    \
            CA[2*(g)+1], CB[nt], acc[2*(g)+1][nt], 0, 0, 0);                         \
    }                                                                                \
    __builtin_amdgcn_s_setprio(0);                                                   \
  } while (0)

    // lead role: reads feed the LDS port while the sibling's MFMAs run
#define GROUP_RW(g, CA, CB, NA, NB, gsrc, goff)  do {                                \
    READS(g, NA, NB, gsrc, goff);                                                    \
    __builtin_amdgcn_sched_barrier(0);                                               \
    MFMAS(g, CA, CB);                                                                \
    __builtin_amdgcn_sched_barrier(0);                                               \
  } while (0)

    // lag role: MFMA first (consumes last-tile registers), reads after
#define GROUP_WR(g, CA, CB, NA, NB, gsrc, goff)  do {                                \
    MFMAS(g, CA, CB);                                                                \
    __builtin_amdgcn_sched_barrier(0);                                               \
    READS(g, NA, NB, gsrc, goff);                                                    \
    __builtin_amdgcn_sched_barrier(0);                                               \
  } while (0)

#define KSTEP(G, u, CA, CB, NA, NB, kt4) do {                                        \
    const int kt  = (kt4) + (u);                                                     \
    const int8_t* bufN = smem + (((u) + 1) & 3) * 32768;                             \
    int8_t* pD = smem + (((u) + 3) & 3) * 32768;                                     \
    const int ktp = (kt + 3 < 64) ? (kt + 3) : 63;                                   \
    const int8_t* _a = gA + (size_t)ktp * 64;                                        \
    const int8_t* _b = gB + (size_t)ktp * 64;                                        \
    asm volatile("s_waitcnt vmcnt(4)" ::: "memory");                                 \
    __builtin_amdgcn_s_barrier();                                                    \
    __builtin_amdgcn_sched_barrier(0);                                               \
    G(0, CA, CB, NA, NB, _a,         0);                                             \
    G(1, CA, CB, NA, NB, _a + rstep, 8192);                                          \
    G(2, CA, CB, NA, NB, _b,         16384);                                         \
    G(3, CA, CB, NA, NB, _b + rstep, 24576);                                         \
  } while (0)

    // ---- prologue: stage tiles 0..2; retire tile 0; load its fragments
    STAGE(0, 0); STAGE(1, 1); STAGE(2, 2);
    asm volatile("s_waitcnt vmcnt(8)" ::: "memory");
    __builtin_amdgcn_s_barrier();
#pragma unroll
    for (int mt = 0; mt < 8; ++mt) aFa[mt] = *(const v4i*)(smem + abase + mt * 1024);
#pragma unroll
    for (int nt = 0; nt < 4; ++nt) bFa[nt] = *(const v4i*)(smem + bbase + nt * 1024);

    if (wid < 4) {  // lead waves: one per SIMD (wid%4 = SIMD id)
        for (int kt4 = 0; kt4 < 64; kt4 += 4) {
            KSTEP(GROUP_RW, 0, aFa, bFa, aFb, bFb, kt4);
            KSTEP(GROUP_RW, 1, aFb, bFb, aFa, bFa, kt4);
            KSTEP(GROUP_RW, 2, aFa, bFa, aFb, bFb, kt4);
            KSTEP(GROUP_RW, 3, aFb, bFb, aFa, bFa, kt4);
        }
    } else {        // lag waves: the SIMD siblings, anti-phased by construction
        for (int kt4 = 0; kt4 < 64; kt4 += 4) {
            KSTEP(GROUP_WR, 0, aFa, bFa, aFb, bFb, kt4);
            KSTEP(GROUP_WR, 1, aFb, bFb, aFa, bFa, kt4);
            KSTEP(GROUP_WR, 2, aFa, bFa, aFb, bFb, kt4);
            KSTEP(GROUP_WR, 3, aFb, bFb, aFa, bFa, kt4);
        }
    }

    // epilogue: C/D layout col = lane&15 (N), row = (lane>>4)*4 + reg (M)
    const int r0  = (lane >> 4) << 2;
    const int col = lane & 15;
#pragma unroll
    for (int mt = 0; mt < 8; ++mt) {
        const int tbase = m0 + wm * 128 + mt * 16 + r0;
        float as[4];
#pragma unroll
        for (int r = 0; r < 4; ++r) as[r] = a_scale[tbase + r];
#pragma unroll
        for (int nt = 0; nt < 4; ++nt) {
            const int o = n0 + wn * 64 + nt * 16 + col;
            const float wsc = w_scale[o];
#pragma unroll
            for (int r = 0; r < 4; ++r) {
                float v = (float)acc[mt][nt][r] * as[r] * wsc;
                out[(size_t)(tbase + r) * 4096 + o] = __half2float(__float2half_rn(v));
            }
        }
    }
#undef KSTEP
#undef GROUP_RW
#undef GROUP_WR
#undef MFMAS
#undef READS
#undef STAGE
}

extern "C" void kernel_launch(void* const* d_in, const int* in_sizes, int n_in,
                              void* d_out, int out_size, void* d_ws, size_t ws_size,
                              hipStream_t stream) {
    const float* input_act = (const float*)d_in[0];  // [4,2048,4096] = [8192,4096]
    const float* weight    = (const float*)d_in[1];  // [4096,4096]
    float* out = (float*)d_out;

    const int K = 4096, O = 4096, T = 8192;

    int8_t* x_q = (int8_t*)d_ws;
    int8_t* w_q = x_q + (size_t)T * K;
    float* a_scale = (float*)(w_q + (size_t)O * K);
    float* w_scale = a_scale + T;

    static bool attr_done = false;
    if (!attr_done) {
        hipFuncSetAttribute(reinterpret_cast<const void*>(gemm_i8),
                            hipFuncAttributeMaxDynamicSharedMemorySize, 131072);
        attr_done = true;
    }

    quant_fused<<<T + O, 256, 0, stream>>>(input_act, weight, x_q, w_q,
                                           a_scale, w_scale);

    dim3 grid(512);  // (8192/256) x (4096/256), XCD-swizzled in-kernel
    gemm_i8<<<grid, 512, 131072, stream>>>(x_q, w_q, a_scale, w_scale, out);
}